// Round 1
// baseline (123.479 us; speedup 1.0000x reference)
//
#include <hip/hip_runtime.h>

#define NUM_CLASSES 80
#define R1 8            // REG_MAX + 1
#define HW 4096         // H*W

__device__ __forceinline__ float sigmoidf(float x) {
    return 1.0f / (1.0f + expf(-x));
}

__device__ __forceinline__ float softplusf(float x) {
    // log(1 + e^x), stable
    return fmaxf(x, 0.0f) + log1pf(expf(-fabsf(x)));
}

__global__ __launch_bounds__(256) void nanodet_loss_kernel(
    const float* __restrict__ anchors,       // [N,4]
    const float* __restrict__ cls_score,     // [B,C,H,W]
    const float* __restrict__ bbox_pred,     // [B,4*R1,H,W]
    const float* __restrict__ label_weights, // [N]
    const float* __restrict__ bbox_targets,  // [N,4]
    const int*   __restrict__ labels,        // [N]
    const int*   __restrict__ nts_p,         // [1]
    const int*   __restrict__ stride_p,      // [1]
    float* __restrict__ out, int N)
{
    const float stride  = (float)stride_p[0];
    const float inv_str = 1.0f / stride;
    const float inv_nts = 1.0f / (float)nts_p[0];

    const int n = blockIdx.x * blockDim.x + threadIdx.x;

    float qfl = 0.0f, lbbox = 0.0f, dfl = 0.0f, wts = 0.0f;

    if (n < N) {
        const int b  = n >> 12;          // n / HW
        const int hw = n & (HW - 1);     // n % HW

        const int lab = labels[n];
        const bool pos = (lab >= 0) && (lab < NUM_CLASSES);
        const int lab_c = pos ? lab : 0;

        // ---------------- cls pass ----------------
        const float* cbase = cls_score + (size_t)b * NUM_CLASSES * HW + hw;
        float xmax = -INFINITY;
        float negsum = 0.0f;
        float xlab = 0.0f;
        #pragma unroll 8
        for (int c = 0; c < NUM_CLASSES; ++c) {
            float x = cbase[(size_t)c * HW];
            xmax = fmaxf(xmax, x);
            float s = sigmoidf(x);
            negsum += softplusf(x) * s * s;
            if (c == lab_c) xlab = x;
        }
        const float wt = pos ? sigmoidf(xmax) : 0.0f;

        // ---------------- geometry ----------------
        const float4 a = reinterpret_cast<const float4*>(anchors)[n];
        const float cx = 0.5f * (a.x + a.z) * inv_str;
        const float cy = 0.5f * (a.y + a.w) * inv_str;

        const float4 t = reinterpret_cast<const float4*>(bbox_targets)[n];
        const float tx0 = t.x * inv_str, ty0 = t.y * inv_str;
        const float tx1 = t.z * inv_str, ty1 = t.w * inv_str;

        // distances for DFL targets (independent of bbox logits)
        float dist[4];
        dist[0] = cx - tx0; dist[1] = cy - ty0;
        dist[2] = tx1 - cx; dist[3] = ty1 - cy;

        // ---------------- bbox distributions ----------------
        const float* bbase = bbox_pred + (size_t)b * (4 * R1) * HW + hw;
        float corners[4];
        float dsum = 0.0f;
        #pragma unroll
        for (int k = 0; k < 4; ++k) {
            float xk[R1];
            float m = -INFINITY;
            #pragma unroll
            for (int j = 0; j < R1; ++j) {
                xk[j] = bbase[(size_t)(k * R1 + j) * HW];
                m = fmaxf(m, xk[j]);
            }
            float se = 0.0f, swe = 0.0f;
            #pragma unroll
            for (int j = 0; j < R1; ++j) {
                float e = expf(xk[j] - m);
                se += e;
                swe += e * (float)j;
            }
            corners[k] = swe / se;
            const float lse = m + logf(se);   // logsumexp

            // DFL for this side: runtime index -> unrolled compare-select
            float d = fminf(fmaxf(dist[k], 0.0f), (float)(R1 - 1) - 0.1f);
            int tl = (int)floorf(d);
            int tr = tl + 1; if (tr > R1 - 1) tr = R1 - 1;
            float x_tl = xk[0], x_tr = xk[0];
            #pragma unroll
            for (int j = 1; j < R1; ++j) {
                if (j == tl) x_tl = xk[j];
                if (j == tr) x_tr = xk[j];
            }
            const float wl = (float)(tl + 1) - d;
            const float wr = d - (float)tl;
            const float ce_l = lse - x_tl;    // -log_softmax[tl]
            const float ce_r = lse - x_tr;
            dsum += ce_l * wl + ce_r * wr;
        }
        dfl = dsum * wt;

        // ---------------- GIoU ----------------
        const float px0 = cx - corners[0], py0 = cy - corners[1];
        const float px1 = cx + corners[2], py1 = cy + corners[3];

        const float ilx = fmaxf(px0, tx0), ily = fmaxf(py0, ty0);
        const float irx = fminf(px1, tx1), iry = fminf(py1, ty1);
        const float iw = fmaxf(irx - ilx, 0.0f), ih = fmaxf(iry - ily, 0.0f);
        const float overlap = iw * ih;
        const float ap = (px1 - px0) * (py1 - py0);
        const float at = (tx1 - tx0) * (ty1 - ty0);
        const float uni = fmaxf(ap + at - overlap, 1e-6f);
        const float iou = overlap / uni;

        const float elx = fminf(px0, tx0), ely = fminf(py0, ty0);
        const float erx = fmaxf(px1, tx1), ery = fmaxf(py1, ty1);
        const float ew = fmaxf(erx - elx, 0.0f), eh = fmaxf(ery - ely, 0.0f);
        const float earea = fmaxf(ew * eh, 1e-6f);
        const float giou = iou - (earea - uni) / earea;

        lbbox = (1.0f - giou) * wt;
        wts = wt;

        // ---------------- QFL ----------------
        const float score = pos ? iou : 0.0f;
        float row = negsum;
        if (pos) {
            const float s  = sigmoidf(xlab);
            const float sp = softplusf(xlab);
            const float negterm = sp * s * s;
            const float sf = score - s;
            const float posl = (sp - xlab * score) * sf * sf;
            row = row - negterm + posl;
        }
        qfl = row * label_weights[n];
    }

    // ---------------- reduction ----------------
    float v0 = qfl * inv_nts;
    float v1 = lbbox * 2.0f;
    float v2 = dfl * 0.0625f;     // 0.25 / 4
    float v3 = wts;

    #pragma unroll
    for (int off = 32; off > 0; off >>= 1) {
        v0 += __shfl_down(v0, off);
        v1 += __shfl_down(v1, off);
        v2 += __shfl_down(v2, off);
        v3 += __shfl_down(v3, off);
    }

    __shared__ float smem[4][4];  // [wave][channel]
    const int wid  = threadIdx.x >> 6;
    const int lane = threadIdx.x & 63;
    if (lane == 0) {
        smem[wid][0] = v0; smem[wid][1] = v1;
        smem[wid][2] = v2; smem[wid][3] = v3;
    }
    __syncthreads();
    if (threadIdx.x == 0) {
        float s0 = smem[0][0] + smem[1][0] + smem[2][0] + smem[3][0];
        float s1 = smem[0][1] + smem[1][1] + smem[2][1] + smem[3][1];
        float s2 = smem[0][2] + smem[1][2] + smem[2][2] + smem[3][2];
        float s3 = smem[0][3] + smem[1][3] + smem[2][3] + smem[3][3];
        atomicAdd(&out[0], s0);
        atomicAdd(&out[1], s1);
        atomicAdd(&out[2], s2);
        atomicAdd(&out[3], s3);
    }
}

extern "C" void kernel_launch(void* const* d_in, const int* in_sizes, int n_in,
                              void* d_out, int out_size, void* d_ws, size_t ws_size,
                              hipStream_t stream) {
    const float* anchors       = (const float*)d_in[0];
    const float* cls_score     = (const float*)d_in[1];
    const float* bbox_pred     = (const float*)d_in[2];
    const float* label_weights = (const float*)d_in[3];
    const float* bbox_targets  = (const float*)d_in[4];
    const int*   labels        = (const int*)d_in[5];
    const int*   nts_p         = (const int*)d_in[6];
    const int*   stride_p      = (const int*)d_in[7];
    float* out = (float*)d_out;

    const int N = in_sizes[5];  // labels count = B*H*W

    hipMemsetAsync(d_out, 0, 4 * sizeof(float), stream);

    const int block = 256;
    const int grid = (N + block - 1) / block;
    nanodet_loss_kernel<<<grid, block, 0, stream>>>(
        anchors, cls_score, bbox_pred, label_weights, bbox_targets,
        labels, nts_p, stride_p, out, N);
}

// Round 2
// 73.002 us; speedup vs baseline: 1.6914x; 1.6914x over previous
//
#include <hip/hip_runtime.h>

#define NUM_CLASSES 80
#define R1 8            // REG_MAX + 1
#define HW 4096         // H*W

#define LOG2E 1.44269504088896f
#define LN2   0.69314718055995f

// fast hardware transcendentals (plenty of precision: outputs are sums of
// 262K O(1) terms with absmax threshold 122.88)
__device__ __forceinline__ float fexp(float x) { return __expf(x); }   // v_mul + v_exp_f32
__device__ __forceinline__ float flog(float x) { return __logf(x); }   // v_log_f32 + v_mul
__device__ __forceinline__ float frcp(float x) { return __builtin_amdgcn_rcpf(x); }

__global__ __launch_bounds__(256) void nanodet_loss_kernel(
    const float* __restrict__ anchors,       // [N,4]
    const float* __restrict__ cls_score,     // [B,C,H,W]
    const float* __restrict__ bbox_pred,     // [B,4*R1,H,W]
    const float* __restrict__ label_weights, // [N]
    const float* __restrict__ bbox_targets,  // [N,4]
    const int*   __restrict__ labels,        // [N]
    const int*   __restrict__ nts_p,         // [1]
    const int*   __restrict__ stride_p,      // [1]
    float* __restrict__ out, int N)
{
    const float stride  = (float)stride_p[0];
    const float inv_str = frcp(stride);
    const float inv_nts = frcp((float)nts_p[0]);

    const int n = blockIdx.x * blockDim.x + threadIdx.x;

    float qfl = 0.0f, lbbox = 0.0f, dfl = 0.0f, wts = 0.0f;

    if (n < N) {
        const int b  = n >> 12;          // n / HW
        const int hw = n & (HW - 1);     // n % HW

        const int lab = labels[n];
        const bool pos = (lab >= 0) && (lab < NUM_CLASSES);
        const int lab_c = pos ? lab : 0;

        // ---------------- cls pass ----------------
        // per class: sig s = 1/(1+exp(-x)); softplus(x) = x - ln(s)
        // neg QFL term = softplus(x) * s^2
        const float* cbase = cls_score + (size_t)b * NUM_CLASSES * HW + hw;
        float xmax = -INFINITY;
        float negsum = 0.0f;
        float xlab = 0.0f;
        #pragma unroll 16
        for (int c = 0; c < NUM_CLASSES; ++c) {
            float x = cbase[(size_t)c * HW];
            xmax = fmaxf(xmax, x);
            float e = fexp(-x);                 // exp(-x)
            float s = frcp(1.0f + e);           // sigmoid
            float sp = x - flog(s);             // softplus(x)
            negsum = fmaf(sp * s, s, negsum);
            if (c == lab_c) xlab = x;
        }
        const float wt = pos ? frcp(1.0f + fexp(-xmax)) : 0.0f;

        // ---------------- geometry ----------------
        const float4 a = reinterpret_cast<const float4*>(anchors)[n];
        const float cx = 0.5f * (a.x + a.z) * inv_str;
        const float cy = 0.5f * (a.y + a.w) * inv_str;

        const float4 t = reinterpret_cast<const float4*>(bbox_targets)[n];
        const float tx0 = t.x * inv_str, ty0 = t.y * inv_str;
        const float tx1 = t.z * inv_str, ty1 = t.w * inv_str;

        float dist[4];
        dist[0] = cx - tx0; dist[1] = cy - ty0;
        dist[2] = tx1 - cx; dist[3] = ty1 - cy;

        // ---------------- bbox distributions ----------------
        const float* bbase = bbox_pred + (size_t)b * (4 * R1) * HW + hw;
        float corners[4];
        float dsum = 0.0f;
        #pragma unroll
        for (int k = 0; k < 4; ++k) {
            float xk[R1];
            float m = -INFINITY;
            #pragma unroll
            for (int j = 0; j < R1; ++j) {
                xk[j] = bbase[(size_t)(k * R1 + j) * HW];
                m = fmaxf(m, xk[j]);
            }
            float se = 0.0f, swe = 0.0f;
            #pragma unroll
            for (int j = 0; j < R1; ++j) {
                float e = fexp(xk[j] - m);
                se += e;
                swe = fmaf(e, (float)j, swe);
            }
            corners[k] = swe * frcp(se);
            const float lse = m + flog(se);     // logsumexp

            // DFL: runtime index -> unrolled compare-select (no scratch)
            float d = fminf(fmaxf(dist[k], 0.0f), (float)(R1 - 1) - 0.1f);
            int tl = (int)d;                    // d >= 0, floor == trunc
            int tr = tl + 1; if (tr > R1 - 1) tr = R1 - 1;
            float x_tl = xk[0], x_tr = xk[0];
            #pragma unroll
            for (int j = 1; j < R1; ++j) {
                if (j == tl) x_tl = xk[j];
                if (j == tr) x_tr = xk[j];
            }
            const float wl = (float)(tl + 1) - d;
            const float wr = d - (float)tl;
            dsum += (lse - x_tl) * wl + (lse - x_tr) * wr;
        }
        dfl = dsum * wt;

        // ---------------- GIoU ----------------
        const float px0 = cx - corners[0], py0 = cy - corners[1];
        const float px1 = cx + corners[2], py1 = cy + corners[3];

        const float ilx = fmaxf(px0, tx0), ily = fmaxf(py0, ty0);
        const float irx = fminf(px1, tx1), iry = fminf(py1, ty1);
        const float iw = fmaxf(irx - ilx, 0.0f), ih = fmaxf(iry - ily, 0.0f);
        const float overlap = iw * ih;
        const float ap = (px1 - px0) * (py1 - py0);
        const float at = (tx1 - tx0) * (ty1 - ty0);
        const float uni = fmaxf(ap + at - overlap, 1e-6f);
        const float iou = overlap * frcp(uni);

        const float elx = fminf(px0, tx0), ely = fminf(py0, ty0);
        const float erx = fmaxf(px1, tx1), ery = fmaxf(py1, ty1);
        const float ew = fmaxf(erx - elx, 0.0f), eh = fmaxf(ery - ely, 0.0f);
        const float earea = fmaxf(ew * eh, 1e-6f);
        const float giou = iou - (earea - uni) * frcp(earea);

        lbbox = (1.0f - giou) * wt;
        wts = wt;

        // ---------------- QFL ----------------
        const float score = pos ? iou : 0.0f;
        float row = negsum;
        if (pos) {
            const float e  = fexp(-xlab);
            const float s  = frcp(1.0f + e);     // sigmoid(xlab)
            const float sp = xlab - flog(s);     // softplus(xlab)
            const float negterm = sp * s * s;
            const float sf = score - s;
            const float posl = (sp - xlab * score) * sf * sf;
            row = row - negterm + posl;
        }
        qfl = row * label_weights[n];
    }

    // ---------------- reduction ----------------
    float v0 = qfl * inv_nts;
    float v1 = lbbox * 2.0f;
    float v2 = dfl * 0.0625f;     // 0.25 / 4
    float v3 = wts;

    #pragma unroll
    for (int off = 32; off > 0; off >>= 1) {
        v0 += __shfl_down(v0, off);
        v1 += __shfl_down(v1, off);
        v2 += __shfl_down(v2, off);
        v3 += __shfl_down(v3, off);
    }

    __shared__ float smem[4][4];  // [wave][channel]
    const int wid  = threadIdx.x >> 6;
    const int lane = threadIdx.x & 63;
    if (lane == 0) {
        smem[wid][0] = v0; smem[wid][1] = v1;
        smem[wid][2] = v2; smem[wid][3] = v3;
    }
    __syncthreads();
    if (threadIdx.x == 0) {
        float s0 = smem[0][0] + smem[1][0] + smem[2][0] + smem[3][0];
        float s1 = smem[0][1] + smem[1][1] + smem[2][1] + smem[3][1];
        float s2 = smem[0][2] + smem[1][2] + smem[2][2] + smem[3][2];
        float s3 = smem[0][3] + smem[1][3] + smem[2][3] + smem[3][3];
        atomicAdd(&out[0], s0);
        atomicAdd(&out[1], s1);
        atomicAdd(&out[2], s2);
        atomicAdd(&out[3], s3);
    }
}

extern "C" void kernel_launch(void* const* d_in, const int* in_sizes, int n_in,
                              void* d_out, int out_size, void* d_ws, size_t ws_size,
                              hipStream_t stream) {
    const float* anchors       = (const float*)d_in[0];
    const float* cls_score     = (const float*)d_in[1];
    const float* bbox_pred     = (const float*)d_in[2];
    const float* label_weights = (const float*)d_in[3];
    const float* bbox_targets  = (const float*)d_in[4];
    const int*   labels        = (const int*)d_in[5];
    const int*   nts_p         = (const int*)d_in[6];
    const int*   stride_p      = (const int*)d_in[7];
    float* out = (float*)d_out;

    const int N = in_sizes[5];  // labels count = B*H*W

    hipMemsetAsync(d_out, 0, 4 * sizeof(float), stream);

    const int block = 256;
    const int grid = (N + block - 1) / block;
    nanodet_loss_kernel<<<grid, block, 0, stream>>>(
        anchors, cls_score, bbox_pred, label_weights, bbox_targets,
        labels, nts_p, stride_p, out, N);
}